// Round 15
// baseline (126.668 us; speedup 1.0000x reference)
//
#include <hip/hip_runtime.h>
#include <hip/hip_bf16.h>
#include <math.h>

#define B_ 32
#define T_ 128
#define C_ 64
#define E_ 8
#define HID_ 32

#define LOG2E 1.44269504088896341f

__device__ __forceinline__ float fast_rcp(float x) { return __builtin_amdgcn_rcpf(x); }
#if __has_builtin(__builtin_amdgcn_exp2f)
__device__ __forceinline__ float fast_exp2(float x) { return __builtin_amdgcn_exp2f(x); }
#else
__device__ __forceinline__ float fast_exp2(float x) { return exp2f(x); }
#endif
__device__ __forceinline__ float fast_sigmoid(float x) {
    return fast_rcp(1.0f + fast_exp2(-LOG2E * x));
}
__device__ __forceinline__ float fast_tanh(float x) {
    float xc = __builtin_amdgcn_fmed3f(x, -15.0f, 15.0f);
    float t = fast_exp2(2.0f * LOG2E * xc);
    return (t - 1.0f) * fast_rcp(t + 1.0f);
}

// ---------------------------------------------------------------------------
// K1 (fat): blocks 0..255 = GRU (8 chains each, h-history buffered in LDS,
// bulk coalesced flush); blocks 256..4351 = ts_imp (one (b,t) each).
// block = 64 threads.
// ---------------------------------------------------------------------------
__global__ __launch_bounds__(64) void k_gru_ts(
    const float* __restrict__ x, const float* __restrict__ W_in, const float* __restrict__ b_in,
    const float* __restrict__ W_ih, const float* __restrict__ W_hh,
    const float* __restrict__ b_ih, const float* __restrict__ b_hh,
    const float* __restrict__ W_ts1, const float* __restrict__ b_ts1,
    const float* __restrict__ W_ts2, const float* __restrict__ b_ts2,
    float* __restrict__ hs, float* __restrict__ fh, float* __restrict__ ts_imp)
{
    const int tid = threadIdx.x;

    __shared__ float wsh[8][C_];          // 2 KB  (ts role reuses as xs/h1)
    __shared__ float xc[8][T_ + 1];       // 4.1 KB
    __shared__ float hsb[T_][68];         // 34.8 KB, pad 68 -> 2-way banks

    if (blockIdx.x >= 256) {
        // ---------------- ts role ----------------
        const int bt = blockIdx.x - 256;
        float* xs = &wsh[0][0];           // reuse LDS
        float* h1 = &xc[0][0];
        xs[tid] = x[bt * C_ + tid];
        __syncthreads();
        if (tid < 16) {
            float a = b_ts1[tid];
#pragma unroll
            for (int k = 0; k < C_; ++k) a = fmaf(xs[k], W_ts1[tid * C_ + k], a);
            h1[tid] = 0.5f * a * (1.0f + erff(a * 0.70710678118654752f));
        }
        __syncthreads();
        if (tid == 0) {
            float s = b_ts2[0];
#pragma unroll
            for (int k = 0; k < 16; ++k) s = fmaf(h1[k], W_ts2[k], s);
            ts_imp[bt] = fast_sigmoid(s);
        }
        return;
    }

    // ---------------- GRU role ----------------
    const int ci = tid >> 3;
    const int e = tid & 7;
    const int chain = blockIdx.x * 8 + ci;
    const int b = chain >> 6;
    const int c = chain & 63;

#pragma unroll
    for (int i = 0; i < 8; ++i) {
        int idx = tid * 8 + i;
        int ci2 = idx >> 6;
        int cc = (blockIdx.x * 8 + ci2) & 63;
        wsh[ci2][idx & 63] = W_in[cc * C_ + (idx & 63)];
    }
    __syncthreads();

    const float bi = b_in[c];
    for (int tt = 0; tt < 16; ++tt) {
        const int t = e * 16 + tt;
        const float4* xr = (const float4*)(x + (b * T_ + t) * C_);
        float a = bi;
#pragma unroll
        for (int k4 = 0; k4 < 16; ++k4) {
            float4 xv = xr[k4];
            a = fmaf(xv.x, wsh[ci][k4 * 4 + 0], a);
            a = fmaf(xv.y, wsh[ci][k4 * 4 + 1], a);
            a = fmaf(xv.z, wsh[ci][k4 * 4 + 2], a);
            a = fmaf(xv.w, wsh[ci][k4 * 4 + 3], a);
        }
        xc[ci][t] = a;
    }
    __syncthreads();

    float wr[E_], wz[E_], wn[E_];
#pragma unroll
    for (int j = 0; j < E_; ++j) {
        wr[j] = W_hh[(c * 24 + 0 * E_ + e) * E_ + j];
        wz[j] = W_hh[(c * 24 + 1 * E_ + e) * E_ + j];
        wn[j] = W_hh[(c * 24 + 2 * E_ + e) * E_ + j];
    }
    const float wir = W_ih[c * 24 + e], wiz = W_ih[c * 24 + E_ + e], win = W_ih[c * 24 + 2 * E_ + e];
    const float cr = b_ih[c * 24 + e] + b_hh[c * 24 + e];
    const float cz = b_ih[c * 24 + E_ + e] + b_hh[c * 24 + E_ + e];
    const float bin_ = b_ih[c * 24 + 2 * E_ + e];
    const float bhn  = b_hh[c * 24 + 2 * E_ + e];

    float h = 0.0f;
    float xv = xc[ci][0];
    for (int t = 0; t < T_; ++t) {
        float xvn = xc[ci][t + 1];
        float hj0 = __shfl(h, 0, 8), hj1 = __shfl(h, 1, 8);
        float hj2 = __shfl(h, 2, 8), hj3 = __shfl(h, 3, 8);
        float hj4 = __shfl(h, 4, 8), hj5 = __shfl(h, 5, 8);
        float hj6 = __shfl(h, 6, 8), hj7 = __shfl(h, 7, 8);
        float grx = fmaf(xv, wir, cr);
        float gzx = fmaf(xv, wiz, cz);
        float gnx = fmaf(xv, win, bin_);
        float r0 = fmaf(hj1, wr[1], hj0 * wr[0]);
        float r1 = fmaf(hj3, wr[3], hj2 * wr[2]);
        float r2 = fmaf(hj5, wr[5], hj4 * wr[4]);
        float r3 = fmaf(hj7, wr[7], hj6 * wr[6]);
        float z0 = fmaf(hj1, wz[1], hj0 * wz[0]);
        float z1 = fmaf(hj3, wz[3], hj2 * wz[2]);
        float z2 = fmaf(hj5, wz[5], hj4 * wz[4]);
        float z3 = fmaf(hj7, wz[7], hj6 * wz[6]);
        float n0 = fmaf(hj1, wn[1], hj0 * wn[0]);
        float n1 = fmaf(hj3, wn[3], hj2 * wn[2]);
        float n2 = fmaf(hj5, wn[5], hj4 * wn[4]);
        float n3 = fmaf(hj7, wn[7], hj6 * wn[6]);
        float gr = grx + ((r0 + r1) + (r2 + r3));
        float gz = gzx + ((z0 + z1) + (z2 + z3));
        float hn = bhn + ((n0 + n1) + (n2 + n3));
        float r = fast_sigmoid(gr);
        float z = fast_sigmoid(gz);
        float nn = fast_tanh(fmaf(r, hn, gnx));
        h = fmaf(z, h - nn, nn);
        hsb[t][tid] = h;               // LDS, off the dependence chain
        xv = xvn;
    }
    fh[chain * E_ + e] = h;
    __syncthreads();

    // bulk flush: 8192 floats = 2048 float4, coalesced
    float4* gdst = (float4*)(hs + (size_t)blockIdx.x * 8 * T_ * E_);
#pragma unroll
    for (int k = 0; k < 32; ++k) {
        int idx4 = k * 64 + tid;
        int fi = idx4 * 4;
        int cc = fi >> 10;             // chain-in-block
        int t = (fi >> 3) & 127;
        int ee = fi & 7;               // 0 or 4
        gdst[idx4] = *(const float4*)&hsb[t][cc * 8 + ee];
    }
}

// ---------------------------------------------------------------------------
// K2 (fat): blocks 0..2047 = attention per (b,c); block 2048 = out0.
// attention: block 256 thr = 4 waves; wave w owns rows [32w,32w+32);
// lane = 2*ri+sh: row = 32w+ri, s in [64sh, 64sh+64). shfl_xor(1) combine.
// ---------------------------------------------------------------------------
__global__ __launch_bounds__(256) void k_attn_out(
    const float* __restrict__ hs, const float* __restrict__ W_qkv, const float* __restrict__ b_qkv,
    const float* __restrict__ W_o, const float* __restrict__ b_o,
    const float* __restrict__ fh, const float* __restrict__ W_out, const float* __restrict__ b_out,
    float* __restrict__ out0, float* __restrict__ feat_imp, float* __restrict__ tsf_imp)
{
    const int tid = threadIdx.x;

    if (blockIdx.x == B_ * C_) {
        // ---------------- out role: 1024 (b,o) pairs over 256 threads ----
#pragma unroll
        for (int pi = tid; pi < B_ * HID_; pi += 256) {
            int bb = pi >> 5, o = pi & 31;
            const float4* hv = (const float4*)(fh + bb * C_ * E_);
            const float4* wv = (const float4*)(W_out + o * C_ * E_);
            float a = b_out[o];
#pragma unroll 16
            for (int k4 = 0; k4 < 128; ++k4) {
                float4 h4 = hv[k4], w4 = wv[k4];
                a = fmaf(h4.x, w4.x, a); a = fmaf(h4.y, w4.y, a);
                a = fmaf(h4.z, w4.z, a); a = fmaf(h4.w, w4.w, a);
            }
            out0[pi] = a;
        }
        return;
    }

    const int bc = blockIdx.x;
    const int b = bc >> 6, c = bc & 63;
    const int w = tid >> 6;
    const int lane = tid & 63;
    const int ri = lane >> 1;
    const int sh = lane & 1;
    const int row = w * 32 + ri;

    __shared__ __align__(16) float ks[T_][E_];    // 4 KB
    __shared__ __align__(16) float us[T_][4];     // 2 KB
    __shared__ float qsT[E_][T_];                 // 4 KB
    __shared__ float red4[4];

    const float qscale = 0.70710678118654752f * LOG2E;

    // staging: tid<128 -> q+k of row tid; tid>=128 -> u of row tid-128
    {
        const int srow = (tid < 128) ? tid : (tid - 128);
        const float4* hp = (const float4*)(hs + (size_t)bc * T_ * E_ + srow * E_);
        float4 h0 = hp[0], h1 = hp[1];
        float hr[E_] = {h0.x, h0.y, h0.z, h0.w, h1.x, h1.y, h1.z, h1.w};
        if (tid < 128) {
            float kv[E_];
#pragma unroll
            for (int f = 0; f < E_; ++f) {
                float a = b_qkv[E_ + f];
#pragma unroll
                for (int j = 0; j < E_; ++j) a = fmaf(hr[j], W_qkv[(E_ + f) * E_ + j], a);
                kv[f] = a;
            }
            ((float4*)&ks[srow][0])[0] = make_float4(kv[0], kv[1], kv[2], kv[3]);
            ((float4*)&ks[srow][0])[1] = make_float4(kv[4], kv[5], kv[6], kv[7]);
#pragma unroll
            for (int f = 0; f < E_; ++f) {
                float a = b_qkv[f];
#pragma unroll
                for (int j = 0; j < E_; ++j) a = fmaf(hr[j], W_qkv[f * E_ + j], a);
                qsT[f][srow] = a * qscale;
            }
        } else {
            float ws[E_];
#pragma unroll
            for (int d = 0; d < E_; ++d) {
                float wv = 0.0f;
#pragma unroll
                for (int fp = 0; fp < E_; ++fp) wv += W_o[fp * E_ + d];
                ws[d] = wv;
            }
            float vv[E_];
#pragma unroll
            for (int f = 0; f < E_; ++f) {
                float a = b_qkv[2 * E_ + f];
#pragma unroll
                for (int j = 0; j < E_; ++j) a = fmaf(hr[j], W_qkv[(2 * E_ + f) * E_ + j], a);
                vv[f] = a;
            }
            float4 uu;
            uu.x = fmaf(vv[1], ws[1], vv[0] * ws[0]);
            uu.y = fmaf(vv[3], ws[3], vv[2] * ws[2]);
            uu.z = fmaf(vv[5], ws[5], vv[4] * ws[4]);
            uu.w = fmaf(vv[7], ws[7], vv[6] * ws[6]);
            *((float4*)&us[srow][0]) = uu;
        }
    }
    __syncthreads();

    // q for this lane's row: qsT bank = row%32 -> conflict-free (pairs broadcast)
    float q[E_];
#pragma unroll
    for (int f = 0; f < E_; ++f) q[f] = qsT[f][row];

    float l[4] = {0.f, 0.f, 0.f, 0.f};
    float S[4] = {0.f, 0.f, 0.f, 0.f};
    const float* kb = &ks[sh * 64][0];
    const float* ub = &us[sh * 64][0];
#pragma unroll 8
    for (int i = 0; i < 64; ++i) {
        float4 k0 = *(const float4*)(kb + i * 8);
        float4 k1 = *(const float4*)(kb + i * 8 + 4);
        float4 uu = *(const float4*)(ub + i * 4);
        float p0 = fast_exp2(fmaf(q[1], k0.y, q[0] * k0.x));
        float p1 = fast_exp2(fmaf(q[3], k0.w, q[2] * k0.z));
        float p2 = fast_exp2(fmaf(q[5], k1.y, q[4] * k1.x));
        float p3 = fast_exp2(fmaf(q[7], k1.w, q[6] * k1.z));
        l[0] += p0; l[1] += p1; l[2] += p2; l[3] += p3;
        S[0] = fmaf(p0, uu.x, S[0]);
        S[1] = fmaf(p1, uu.y, S[1]);
        S[2] = fmaf(p2, uu.z, S[2]);
        S[3] = fmaf(p3, uu.w, S[3]);
    }

    // combine the two s-halves of each row (partner lane)
#pragma unroll
    for (int i = 0; i < 4; ++i) {
        l[i] += __shfl_xor(l[i], 1);
        S[i] += __shfl_xor(S[i], 1);
    }

    float bsum = 0.0f;
#pragma unroll
    for (int fp = 0; fp < E_; ++fp) bsum += b_o[fp];
    float Sv = bsum;
#pragma unroll
    for (int hh = 0; hh < 4; ++hh) Sv = fmaf(S[hh], fast_rcp(l[hh]), Sv);

    if (sh == 0)
        tsf_imp[(size_t)b * T_ * C_ + (size_t)row * C_ + c] = fast_sigmoid(Sv);

    // feat: butterfly over offsets 2..32 sums each wave's 32 rows (per parity)
    float fsum = Sv;
#pragma unroll
    for (int off = 2; off <= 32; off <<= 1) fsum += __shfl_xor(fsum, off);
    if (lane == 0) red4[w] = fsum;
    __syncthreads();
    if (tid == 0)
        feat_imp[bc] = fast_sigmoid(red4[0] + red4[1] + red4[2] + red4[3]);
}

// ---------------------------------------------------------------------------
extern "C" void kernel_launch(void* const* d_in, const int* in_sizes, int n_in,
                              void* d_out, int out_size, void* d_ws, size_t ws_size,
                              hipStream_t stream) {
    (void)in_sizes; (void)n_in; (void)out_size; (void)ws_size;

    float* out0 = (float*)d_out;                 // (B, HID)    1024
    float* feat = out0 + B_ * HID_;              // (B, C)      2048
    float* tsim = feat + B_ * C_;                // (B, T)      4096
    float* tsf  = tsim + B_ * T_;                // (B, T, C) 262144

    const float* x     = (const float*)d_in[0];
    const float* W_in  = (const float*)d_in[1];
    const float* b_in  = (const float*)d_in[2];
    const float* W_ts1 = (const float*)d_in[3];
    const float* b_ts1 = (const float*)d_in[4];
    const float* W_ts2 = (const float*)d_in[5];
    const float* b_ts2 = (const float*)d_in[6];
    const float* W_ih  = (const float*)d_in[7];
    const float* W_hh  = (const float*)d_in[8];
    const float* b_ih  = (const float*)d_in[9];
    const float* b_hh  = (const float*)d_in[10];
    const float* W_qkv = (const float*)d_in[11];
    const float* b_qkv = (const float*)d_in[12];
    const float* W_o   = (const float*)d_in[13];
    const float* b_o   = (const float*)d_in[14];
    const float* W_out = (const float*)d_in[15];
    const float* b_out = (const float*)d_in[16];

    float* fhb = (float*)d_ws;                   // fh 16K
    float* hsb = fhb + B_ * C_ * E_;             // hs 8M

    hipLaunchKernelGGL(k_gru_ts, dim3(256 + B_ * T_), dim3(64), 0, stream,
                       x, W_in, b_in, W_ih, W_hh, b_ih, b_hh,
                       W_ts1, b_ts1, W_ts2, b_ts2, hsb, fhb, tsim);
    hipLaunchKernelGGL(k_attn_out, dim3(B_ * C_ + 1), dim3(256), 0, stream,
                       hsb, W_qkv, b_qkv, W_o, b_o,
                       fhb, W_out, b_out, out0, feat, tsf);
}

// Round 16
// 111.120 us; speedup vs baseline: 1.1399x; 1.1399x over previous
//
#include <hip/hip_runtime.h>
#include <hip/hip_bf16.h>
#include <math.h>

#define B_ 32
#define T_ 128
#define C_ 64
#define E_ 8
#define HID_ 32

#define LOG2E 1.44269504088896341f

__device__ __forceinline__ float fast_rcp(float x) { return __builtin_amdgcn_rcpf(x); }
__device__ __forceinline__ float fast_exp2(float x) { return exp2f(x); }
__device__ __forceinline__ float fast_sigmoid(float x) {
    return fast_rcp(1.0f + fast_exp2(-LOG2E * x));
}
__device__ __forceinline__ float fast_tanh(float x) {
    float xc = __builtin_amdgcn_fmed3f(x, -15.0f, 15.0f);
    float t = fast_exp2(2.0f * LOG2E * xc);
    return (t - 1.0f) * fast_rcp(t + 1.0f);
}

// ---------------------------------------------------------------------------
// K0: xp[bt, d] = b_in[d] + x[bt,:] . W_in[d,:]   ('btc,dc->btd')
// grid = B*T, block = 64 (massively parallel, ~2 us)
// ---------------------------------------------------------------------------
__global__ __launch_bounds__(64) void k_pre(
    const float* __restrict__ x, const float* __restrict__ W_in, const float* __restrict__ b_in,
    float* __restrict__ xp)
{
    const int bt = blockIdx.x;
    const int tid = threadIdx.x;
    __shared__ __align__(16) float4 xs4[16];
    if (tid < 16) xs4[tid] = ((const float4*)(x + bt * C_))[tid];
    __syncthreads();
    float a = b_in[tid];
    const float4* w4 = (const float4*)(W_in + tid * C_);
#pragma unroll
    for (int k4 = 0; k4 < 16; ++k4) {
        float4 xv = xs4[k4];
        float4 wv = w4[k4];
        a = fmaf(xv.x, wv.x, a); a = fmaf(xv.y, wv.y, a);
        a = fmaf(xv.z, wv.z, a); a = fmaf(xv.w, wv.w, a);
    }
    xp[bt * C_ + tid] = a;
}

// ---------------------------------------------------------------------------
// K1: GRU, 4 lanes per chain (2 hidden units each). 16 chains per 64-thread
// block, grid = 128. h-exchange via intra-quad shfl_xor (no wide shuffles);
// weights permuted at load time so each lane's dot pairs align with the
// quad-gathered h pairs.
// ---------------------------------------------------------------------------
__global__ __launch_bounds__(64) void k_gru(
    const float* __restrict__ xp, const float* __restrict__ W_ih, const float* __restrict__ W_hh,
    const float* __restrict__ b_ih, const float* __restrict__ b_hh,
    float* __restrict__ hs, float* __restrict__ fh)
{
    const int tid = threadIdx.x;
    const int ci = tid >> 2;                    // chain-in-block 0..15
    const int q  = tid & 3;                     // lane-in-quad; units 2q, 2q+1
    const int chain = blockIdx.x * 16 + ci;
    const int c = chain & 63;

    __shared__ float xc[16][T_ + 1];

    // stage xp columns for this block's 16 chains (same b, contiguous c)
    const int c_base = (blockIdx.x & 3) * 16;
    const int bb = blockIdx.x >> 2;
    for (int idx = tid; idx < 16 * T_; idx += 64) {
        int cci = idx & 15;
        int t = idx >> 4;
        xc[cci][t] = xp[(bb * T_ + t) * C_ + c_base + cci];
    }
    __syncthreads();

    // load-time permuted weights: pair m comes from lane q^m (units 2(q^m)+p)
    float wr[2][8], wz[2][8], wn[2][8];
    float wir[2], wiz[2], win_[2], cr[2], cz[2], bin_[2], bhn[2];
#pragma unroll
    for (int u = 0; u < 2; ++u) {
        const int e = 2 * q + u;
#pragma unroll
        for (int m = 0; m < 4; ++m) {
#pragma unroll
            for (int p = 0; p < 2; ++p) {
                const int j = 2 * (q ^ m) + p;
                wr[u][2 * m + p] = W_hh[(c * 24 + 0  + e) * 8 + j];
                wz[u][2 * m + p] = W_hh[(c * 24 + 8  + e) * 8 + j];
                wn[u][2 * m + p] = W_hh[(c * 24 + 16 + e) * 8 + j];
            }
        }
        wir[u] = W_ih[c * 24 + e];
        wiz[u] = W_ih[c * 24 + 8 + e];
        win_[u] = W_ih[c * 24 + 16 + e];
        cr[u] = b_ih[c * 24 + e] + b_hh[c * 24 + e];
        cz[u] = b_ih[c * 24 + 8 + e] + b_hh[c * 24 + 8 + e];
        bin_[u] = b_ih[c * 24 + 16 + e];
        bhn[u]  = b_hh[c * 24 + 16 + e];
    }

    float ha = 0.0f, hb = 0.0f;                 // h[2q], h[2q+1]
    float* hop = hs + (size_t)chain * T_ * E_ + 2 * q;
    float xv = xc[ci][0];
    for (int t = 0; t < T_; ++t) {
        float xvn = xc[ci][t + 1];              // pad makes t=127 safe
        // quad all-gather of (ha, hb): pairs in m-order
        float pa1 = __shfl_xor(ha, 1), pb1 = __shfl_xor(hb, 1);
        float pa2 = __shfl_xor(ha, 2), pb2 = __shfl_xor(hb, 2);
        float pa3 = __shfl_xor(pa1, 2), pb3 = __shfl_xor(pb1, 2);
        const float pa[4] = {ha, pa1, pa2, pa3};
        const float pb[4] = {hb, pb1, pb2, pb3};
        float hnew[2];
#pragma unroll
        for (int u = 0; u < 2; ++u) {
            float g0 = fmaf(pb[0], wr[u][1], pa[0] * wr[u][0]);
            float g1 = fmaf(pb[1], wr[u][3], pa[1] * wr[u][2]);
            float g2 = fmaf(pb[2], wr[u][5], pa[2] * wr[u][4]);
            float g3 = fmaf(pb[3], wr[u][7], pa[3] * wr[u][6]);
            float gr = fmaf(xv, wir[u], cr[u]) + ((g0 + g1) + (g2 + g3));
            float z0 = fmaf(pb[0], wz[u][1], pa[0] * wz[u][0]);
            float z1 = fmaf(pb[1], wz[u][3], pa[1] * wz[u][2]);
            float z2 = fmaf(pb[2], wz[u][5], pa[2] * wz[u][4]);
            float z3 = fmaf(pb[3], wz[u][7], pa[3] * wz[u][6]);
            float gz = fmaf(xv, wiz[u], cz[u]) + ((z0 + z1) + (z2 + z3));
            float n0 = fmaf(pb[0], wn[u][1], pa[0] * wn[u][0]);
            float n1 = fmaf(pb[1], wn[u][3], pa[1] * wn[u][2]);
            float n2 = fmaf(pb[2], wn[u][5], pa[2] * wn[u][4]);
            float n3 = fmaf(pb[3], wn[u][7], pa[3] * wn[u][6]);
            float hn = bhn[u] + ((n0 + n1) + (n2 + n3));
            float gn = fmaf(xv, win_[u], bin_[u]);
            float r = fast_sigmoid(gr);
            float z = fast_sigmoid(gz);
            float nn = fast_tanh(fmaf(r, hn, gn));
            float hu = (u == 0) ? ha : hb;
            hnew[u] = fmaf(z, hu - nn, nn);
        }
        ha = hnew[0]; hb = hnew[1];
        *(float2*)(hop + (size_t)t * E_) = make_float2(ha, hb);
        xv = xvn;
    }
    fh[chain * E_ + 2 * q] = ha;
    fh[chain * E_ + 2 * q + 1] = hb;
}

// ---------------------------------------------------------------------------
// K2: attention (round-14 proven version). grid = B*C, block = 256:
// t2 = tid&63 (rows t2, t2+64), sq = tid>>6 (s in [32sq,32sq+32)).
// Wave-uniform sq -> broadcast LDS reads; q via transposed qsT.
// ---------------------------------------------------------------------------
__global__ __launch_bounds__(256) void k_attn(
    const float* __restrict__ hs, const float* __restrict__ W_qkv, const float* __restrict__ b_qkv,
    const float* __restrict__ W_o, const float* __restrict__ b_o,
    float* __restrict__ feat_imp, float* __restrict__ tsf_imp)
{
    const int bc = blockIdx.x;
    const int b = bc >> 6, c = bc & 63;
    const int tid = threadIdx.x;
    const int t2 = tid & 63;
    const int sq = tid >> 6;

    __shared__ __align__(16) float ks[T_][E_];
    __shared__ __align__(16) float us[T_][4];
    __shared__ float qsT[E_][T_];
    __shared__ float pacc[3][T_][8];
    __shared__ float red[T_];

    const float qscale = 0.70710678118654752f * LOG2E;

    // staging: tid<128 -> q+k of row tid; tid>=128 -> u of row tid-128
    {
        const int row = (tid < 128) ? tid : (tid - 128);
        const float4* hp = (const float4*)(hs + (size_t)bc * T_ * E_ + row * E_);
        float4 h0 = hp[0], h1 = hp[1];
        float hr[E_] = {h0.x, h0.y, h0.z, h0.w, h1.x, h1.y, h1.z, h1.w};
        if (tid < 128) {
            float kv[E_];
#pragma unroll
            for (int f = 0; f < E_; ++f) {
                float a = b_qkv[E_ + f];
#pragma unroll
                for (int j = 0; j < E_; ++j) a = fmaf(hr[j], W_qkv[(E_ + f) * E_ + j], a);
                kv[f] = a;
            }
            ((float4*)&ks[row][0])[0] = make_float4(kv[0], kv[1], kv[2], kv[3]);
            ((float4*)&ks[row][0])[1] = make_float4(kv[4], kv[5], kv[6], kv[7]);
#pragma unroll
            for (int f = 0; f < E_; ++f) {
                float a = b_qkv[f];
#pragma unroll
                for (int j = 0; j < E_; ++j) a = fmaf(hr[j], W_qkv[f * E_ + j], a);
                qsT[f][row] = a * qscale;
            }
        } else {
            float ws[E_];
#pragma unroll
            for (int d = 0; d < E_; ++d) {
                float wv = 0.0f;
#pragma unroll
                for (int fp = 0; fp < E_; ++fp) wv += W_o[fp * E_ + d];
                ws[d] = wv;
            }
            float vv[E_];
#pragma unroll
            for (int f = 0; f < E_; ++f) {
                float a = b_qkv[2 * E_ + f];
#pragma unroll
                for (int j = 0; j < E_; ++j) a = fmaf(hr[j], W_qkv[(2 * E_ + f) * E_ + j], a);
                vv[f] = a;
            }
            float4 uu;
            uu.x = fmaf(vv[1], ws[1], vv[0] * ws[0]);
            uu.y = fmaf(vv[3], ws[3], vv[2] * ws[2]);
            uu.z = fmaf(vv[5], ws[5], vv[4] * ws[4]);
            uu.w = fmaf(vv[7], ws[7], vv[6] * ws[6]);
            *((float4*)&us[row][0]) = uu;
        }
    }
    __syncthreads();

    float q0[E_], q1[E_];
#pragma unroll
    for (int f = 0; f < E_; ++f) { q0[f] = qsT[f][t2]; q1[f] = qsT[f][t2 + 64]; }

    float l0[4] = {0.f,0.f,0.f,0.f}, S0[4] = {0.f,0.f,0.f,0.f};
    float l1[4] = {0.f,0.f,0.f,0.f}, S1[4] = {0.f,0.f,0.f,0.f};
    const float* kb = &ks[sq * 32][0];
    const float* ub = &us[sq * 32][0];
#pragma unroll 8
    for (int i = 0; i < 32; ++i) {
        float4 k0 = *(const float4*)(kb + i * 8);
        float4 k1 = *(const float4*)(kb + i * 8 + 4);
        float4 uu = *(const float4*)(ub + i * 4);
        float p00 = fast_exp2(fmaf(q0[1], k0.y, q0[0] * k0.x));
        float p01 = fast_exp2(fmaf(q0[3], k0.w, q0[2] * k0.z));
        float p02 = fast_exp2(fmaf(q0[5], k1.y, q0[4] * k1.x));
        float p03 = fast_exp2(fmaf(q0[7], k1.w, q0[6] * k1.z));
        float p10 = fast_exp2(fmaf(q1[1], k0.y, q1[0] * k0.x));
        float p11 = fast_exp2(fmaf(q1[3], k0.w, q1[2] * k0.z));
        float p12 = fast_exp2(fmaf(q1[5], k1.y, q1[4] * k1.x));
        float p13 = fast_exp2(fmaf(q1[7], k1.w, q1[6] * k1.z));
        l0[0] += p00; l0[1] += p01; l0[2] += p02; l0[3] += p03;
        l1[0] += p10; l1[1] += p11; l1[2] += p12; l1[3] += p13;
        S0[0] = fmaf(p00, uu.x, S0[0]); S0[1] = fmaf(p01, uu.y, S0[1]);
        S0[2] = fmaf(p02, uu.z, S0[2]); S0[3] = fmaf(p03, uu.w, S0[3]);
        S1[0] = fmaf(p10, uu.x, S1[0]); S1[1] = fmaf(p11, uu.y, S1[1]);
        S1[2] = fmaf(p12, uu.z, S1[2]); S1[3] = fmaf(p13, uu.w, S1[3]);
    }

    if (sq > 0) {
        float* pr = &pacc[sq - 1][t2][0];
#pragma unroll
        for (int i = 0; i < 4; ++i) { pr[i] = l0[i]; pr[4 + i] = S0[i]; }
        pr = &pacc[sq - 1][t2 + 64][0];
#pragma unroll
        for (int i = 0; i < 4; ++i) { pr[i] = l1[i]; pr[4 + i] = S1[i]; }
    }
    __syncthreads();

    if (sq == 0) {
        float bsum = 0.0f;
#pragma unroll
        for (int fp = 0; fp < E_; ++fp) bsum += b_o[fp];
#pragma unroll
        for (int qq = 0; qq < 3; ++qq) {
#pragma unroll
            for (int i = 0; i < 4; ++i) {
                l0[i] += pacc[qq][t2][i];       S0[i] += pacc[qq][t2][4 + i];
                l1[i] += pacc[qq][t2 + 64][i];  S1[i] += pacc[qq][t2 + 64][4 + i];
            }
        }
        float Sa = bsum, Sb = bsum;
#pragma unroll
        for (int hh = 0; hh < 4; ++hh) {
            Sa = fmaf(S0[hh], fast_rcp(l0[hh]), Sa);
            Sb = fmaf(S1[hh], fast_rcp(l1[hh]), Sb);
        }
        tsf_imp[(size_t)b * T_ * C_ + (size_t)t2 * C_ + c] = fast_sigmoid(Sa);
        tsf_imp[(size_t)b * T_ * C_ + (size_t)(t2 + 64) * C_ + c] = fast_sigmoid(Sb);
        red[t2] = Sa;
        red[t2 + 64] = Sb;
    }
    __syncthreads();
    for (int off = 64; off > 0; off >>= 1) {
        if (tid < off) red[tid] += red[tid + off];
        __syncthreads();
    }
    if (tid == 0) feat_imp[bc] = fast_sigmoid(red[0]);
}

// ---------------------------------------------------------------------------
// K3: ts_imp. grid = B*T, block = 64.
// ---------------------------------------------------------------------------
__global__ __launch_bounds__(64) void k_ts(
    const float* __restrict__ x,
    const float* __restrict__ W_ts1, const float* __restrict__ b_ts1,
    const float* __restrict__ W_ts2, const float* __restrict__ b_ts2,
    float* __restrict__ ts_imp)
{
    const int bt = blockIdx.x;
    const int tid = threadIdx.x;
    __shared__ float xs[C_];
    __shared__ float h1[16];
    xs[tid] = x[bt * C_ + tid];
    __syncthreads();
    if (tid < 16) {
        float a = b_ts1[tid];
#pragma unroll
        for (int k = 0; k < C_; ++k) a = fmaf(xs[k], W_ts1[tid * C_ + k], a);
        h1[tid] = 0.5f * a * (1.0f + erff(a * 0.70710678118654752f));
    }
    __syncthreads();
    if (tid == 0) {
        float s = b_ts2[0];
#pragma unroll
        for (int k = 0; k < 16; ++k) s = fmaf(h1[k], W_ts2[k], s);
        ts_imp[bt] = fast_sigmoid(s);
    }
}

// ---------------------------------------------------------------------------
// K4: out0[b,o] = b_out[o] + sum_k fh[b*C..][k] * W_out[o,k]. grid = B.
// ---------------------------------------------------------------------------
__global__ __launch_bounds__(64) void k_out(
    const float* __restrict__ fh, const float* __restrict__ W_out, const float* __restrict__ b_out,
    float* __restrict__ out0)
{
    const int b = blockIdx.x;
    const int tid = threadIdx.x;
    __shared__ float hf[C_ * E_];
    const float4* src = (const float4*)(fh + (b * C_ + tid) * E_);
    float4* dst = (float4*)(hf + tid * E_);
    dst[0] = src[0];
    dst[1] = src[1];
    __syncthreads();
    if (tid < HID_) {
        float a = b_out[tid];
        const float* wo = W_out + tid * (C_ * E_);
        for (int k = 0; k < C_ * E_; ++k) a = fmaf(hf[k], wo[k], a);
        out0[b * HID_ + tid] = a;
    }
}

// ---------------------------------------------------------------------------
extern "C" void kernel_launch(void* const* d_in, const int* in_sizes, int n_in,
                              void* d_out, int out_size, void* d_ws, size_t ws_size,
                              hipStream_t stream) {
    (void)in_sizes; (void)n_in; (void)out_size; (void)ws_size;

    float* out0 = (float*)d_out;                 // (B, HID)    1024
    float* feat = out0 + B_ * HID_;              // (B, C)      2048
    float* tsim = feat + B_ * C_;                // (B, T)      4096
    float* tsf  = tsim + B_ * T_;                // (B, T, C) 262144

    const float* x     = (const float*)d_in[0];
    const float* W_in  = (const float*)d_in[1];
    const float* b_in  = (const float*)d_in[2];
    const float* W_ts1 = (const float*)d_in[3];
    const float* b_ts1 = (const float*)d_in[4];
    const float* W_ts2 = (const float*)d_in[5];
    const float* b_ts2 = (const float*)d_in[6];
    const float* W_ih  = (const float*)d_in[7];
    const float* W_hh  = (const float*)d_in[8];
    const float* b_ih  = (const float*)d_in[9];
    const float* b_hh  = (const float*)d_in[10];
    const float* W_qkv = (const float*)d_in[11];
    const float* b_qkv = (const float*)d_in[12];
    const float* W_o   = (const float*)d_in[13];
    const float* b_o   = (const float*)d_in[14];
    const float* W_out = (const float*)d_in[15];
    const float* b_out = (const float*)d_in[16];

    // ws layout (f32): fh (64KB) | xp (1MB) | hs (8MB)
    float* fhb = (float*)d_ws;
    float* xpb = fhb + B_ * C_ * E_;
    float* hsb = xpb + (size_t)B_ * T_ * C_;

    hipLaunchKernelGGL(k_pre, dim3(B_ * T_), dim3(64), 0, stream, x, W_in, b_in, xpb);
    hipLaunchKernelGGL(k_gru, dim3(B_ * C_ / 16), dim3(64), 0, stream,
                       xpb, W_ih, W_hh, b_ih, b_hh, hsb, fhb);
    hipLaunchKernelGGL(k_attn, dim3(B_ * C_), dim3(256), 0, stream,
                       hsb, W_qkv, b_qkv, W_o, b_o, feat, tsf);
    hipLaunchKernelGGL(k_ts, dim3(B_ * T_), dim3(64), 0, stream,
                       x, W_ts1, b_ts1, W_ts2, b_ts2, tsim);
    hipLaunchKernelGGL(k_out, dim3(B_), dim3(64), 0, stream,
                       fhb, W_out, b_out, out0);
}